// Round 1
// baseline (262.642 us; speedup 1.0000x reference)
//
#include <hip/hip_runtime.h>

// HyperedgeMeanAggregator: out[h, :] = mean over entries e with seg_ids[e]==h
// of embed_table[node_idx[e], :].  seg_ids is SORTED -> each hyperedge is a
// contiguous run of entries. One 64-thread block per hyperedge; lane l owns
// feature dims [2l, 2l+1] (float2), so each entry's 128-float row is read as
// one fully-coalesced 512B wave transaction.

#define FEAT_DIM 128

__device__ __forceinline__ int lower_bound_i32(const int* __restrict__ a, int n, int key) {
    int lo = 0, hi = n;
    while (lo < hi) {
        int mid = (lo + hi) >> 1;
        if (a[mid] < key) lo = mid + 1; else hi = mid;
    }
    return lo;
}

__global__ __launch_bounds__(64)
void hyperedge_mean_kernel(const float* __restrict__ embed,
                           const int* __restrict__ node_idx,
                           const int* __restrict__ seg_ids,
                           float* __restrict__ out,
                           int E) {
    const int h = blockIdx.x;
    const int lane = threadIdx.x;  // 0..63, owns dims 2*lane, 2*lane+1

    // Wave-uniform binary search for segment bounds (seg_ids sorted).
    const int start = lower_bound_i32(seg_ids, E, h);
    const int end   = lower_bound_i32(seg_ids, E, h + 1);

    float accx = 0.f, accy = 0.f;

    int i = start;
    // Unroll x4: 4 independent gathers in flight to hide cache latency.
    for (; i + 4 <= end; i += 4) {
        const int n0 = node_idx[i + 0];
        const int n1 = node_idx[i + 1];
        const int n2 = node_idx[i + 2];
        const int n3 = node_idx[i + 3];
        const float2 v0 = ((const float2*)(embed + (size_t)n0 * FEAT_DIM))[lane];
        const float2 v1 = ((const float2*)(embed + (size_t)n1 * FEAT_DIM))[lane];
        const float2 v2 = ((const float2*)(embed + (size_t)n2 * FEAT_DIM))[lane];
        const float2 v3 = ((const float2*)(embed + (size_t)n3 * FEAT_DIM))[lane];
        accx += v0.x + v1.x + v2.x + v3.x;
        accy += v0.y + v1.y + v2.y + v3.y;
    }
    for (; i < end; ++i) {
        const int n = node_idx[i];
        const float2 v = ((const float2*)(embed + (size_t)n * FEAT_DIM))[lane];
        accx += v.x;
        accy += v.y;
    }

    const int cnt = end - start;
    const float inv = 1.0f / (float)(cnt > 0 ? cnt : 1);
    float2 r;
    r.x = accx * inv;
    r.y = accy * inv;
    ((float2*)(out + (size_t)h * FEAT_DIM))[lane] = r;
}

extern "C" void kernel_launch(void* const* d_in, const int* in_sizes, int n_in,
                              void* d_out, int out_size, void* d_ws, size_t ws_size,
                              hipStream_t stream) {
    const float* embed    = (const float*)d_in[0];
    const int*   node_idx = (const int*)d_in[1];
    const int*   seg_ids  = (const int*)d_in[2];
    float*       out      = (float*)d_out;

    const int E = in_sizes[1];             // total incidence entries
    const int H = out_size / FEAT_DIM;     // number of hyperedges

    hyperedge_mean_kernel<<<dim3(H), dim3(64), 0, stream>>>(
        embed, node_idx, seg_ids, out, E);
}

// Round 2
// 257.724 us; speedup vs baseline: 1.0191x; 1.0191x over previous
//
#include <hip/hip_runtime.h>

// HyperedgeMeanAggregator: out[h,:] = mean of embed[node_idx[e],:] over the
// contiguous run of entries e with seg_ids[e]==h (seg_ids sorted).
//
// Round 2 structure:
//   Kernel 1 (seg_offsets): one pass over seg_ids -> off[0..H] in d_ws.
//     off[h] = first entry index with seg_ids >= h; off[H] = E.
//   Kernel 2 (main): one 64-thread block per hyperedge.
//     - 2 cached loads for [start,end) instead of binary searches.
//     - ONE coalesced load grabs up to 64 member indices into a register;
//       per-entry broadcast via __shfl (LDS pipe, off the memory chain).
//     - Half-wave per row: lane owns dims [4*(lane&31) .. +3] of entry
//       (j + 2k + (lane>>5)); each float4 load covers 2 rows, unroll x16
//       entries = 8 independent 512B-row gathers in flight.
//     - Tail handled by clamping the shuffle source (duplicate loads hit L1)
//       and predicating the accumulate.

#define D 128

__global__ __launch_bounds__(256)
void seg_offsets_kernel(const int* __restrict__ seg, int E, int H,
                        int* __restrict__ off) {
    const int e = blockIdx.x * blockDim.x + threadIdx.x;
    if (e >= E) return;
    const int s = seg[e];
    const int prev = (e == 0) ? -1 : seg[e - 1];
    for (int h = prev + 1; h <= s; ++h) off[h] = e;   // usually 0 or 1 iters
    if (e == E - 1) {
        for (int h = s + 1; h <= H; ++h) off[h] = E;  // trailing empty segs
    }
}

__global__ __launch_bounds__(64)
void hyperedge_mean_kernel(const float* __restrict__ embed,
                           const int* __restrict__ node_idx,
                           const int* __restrict__ off,
                           float* __restrict__ out) {
    const int h    = blockIdx.x;
    const int lane = threadIdx.x;      // 0..63
    const int half = lane >> 5;        // which of 2 rows per load
    const int col  = (lane & 31) << 2; // feature dims col..col+3

    const int start = off[h];
    const int end   = off[h + 1];

    float4 acc = make_float4(0.f, 0.f, 0.f, 0.f);

    for (int base = start; base < end; base += 64) {
        const int nchunk = min(end - base, 64);
        // One coalesced load: all member indices of this chunk into registers.
        const int myidx = node_idx[base + min(lane, nchunk - 1)];

        for (int j = 0; j < nchunk; j += 16) {
            // 8 independent row-gathers (16 entries) in flight.
            const int i0 = __shfl(myidx, min(j +  0 + half, nchunk - 1), 64);
            const int i1 = __shfl(myidx, min(j +  2 + half, nchunk - 1), 64);
            const int i2 = __shfl(myidx, min(j +  4 + half, nchunk - 1), 64);
            const int i3 = __shfl(myidx, min(j +  6 + half, nchunk - 1), 64);
            const int i4 = __shfl(myidx, min(j +  8 + half, nchunk - 1), 64);
            const int i5 = __shfl(myidx, min(j + 10 + half, nchunk - 1), 64);
            const int i6 = __shfl(myidx, min(j + 12 + half, nchunk - 1), 64);
            const int i7 = __shfl(myidx, min(j + 14 + half, nchunk - 1), 64);

            const float4 v0 = *(const float4*)(embed + (size_t)i0 * D + col);
            const float4 v1 = *(const float4*)(embed + (size_t)i1 * D + col);
            const float4 v2 = *(const float4*)(embed + (size_t)i2 * D + col);
            const float4 v3 = *(const float4*)(embed + (size_t)i3 * D + col);
            const float4 v4 = *(const float4*)(embed + (size_t)i4 * D + col);
            const float4 v5 = *(const float4*)(embed + (size_t)i5 * D + col);
            const float4 v6 = *(const float4*)(embed + (size_t)i6 * D + col);
            const float4 v7 = *(const float4*)(embed + (size_t)i7 * D + col);

#define ACCUM(K, V)                                                         \
            if (j + 2 * (K) + half < nchunk) {                              \
                acc.x += (V).x; acc.y += (V).y;                             \
                acc.z += (V).z; acc.w += (V).w;                             \
            }
            ACCUM(0, v0) ACCUM(1, v1) ACCUM(2, v2) ACCUM(3, v3)
            ACCUM(4, v4) ACCUM(5, v5) ACCUM(6, v6) ACCUM(7, v7)
#undef ACCUM
        }
    }

    // Combine the two half-wave partial sums (even/odd entries, same dims).
    acc.x += __shfl_xor(acc.x, 32, 64);
    acc.y += __shfl_xor(acc.y, 32, 64);
    acc.z += __shfl_xor(acc.z, 32, 64);
    acc.w += __shfl_xor(acc.w, 32, 64);

    if (half == 0) {
        const int cnt = end - start;
        const float inv = 1.0f / (float)(cnt > 0 ? cnt : 1);
        float4 r;
        r.x = acc.x * inv; r.y = acc.y * inv;
        r.z = acc.z * inv; r.w = acc.w * inv;
        *(float4*)(out + (size_t)h * D + col) = r;
    }
}

extern "C" void kernel_launch(void* const* d_in, const int* in_sizes, int n_in,
                              void* d_out, int out_size, void* d_ws, size_t ws_size,
                              hipStream_t stream) {
    const float* embed    = (const float*)d_in[0];
    const int*   node_idx = (const int*)d_in[1];
    const int*   seg_ids  = (const int*)d_in[2];
    float*       out      = (float*)d_out;

    const int E = in_sizes[1];          // total incidence entries
    const int H = out_size / D;         // number of hyperedges

    int* off = (int*)d_ws;              // (H+1) ints of scratch

    seg_offsets_kernel<<<dim3((E + 255) / 256), dim3(256), 0, stream>>>(
        seg_ids, E, H, off);
    hyperedge_mean_kernel<<<dim3(H), dim3(64), 0, stream>>>(
        embed, node_idx, off, out);
}